// Round 9
// baseline (137.248 us; speedup 1.0000x reference)
//
#include <hip/hip_runtime.h>

typedef __attribute__((ext_vector_type(8))) short bf16x8;
typedef __attribute__((ext_vector_type(4))) float f32x4;
typedef __attribute__((ext_vector_type(16))) float f32x16;

#define NB 2
#define SEQ 4096
#define NHD 8
#define HDIM 32
#define DMODEL 256

// scale * log2(e) folded into Q so scores are directly exp2 arguments
#define QSCALE 0.25503506f

__device__ __forceinline__ short f2bf(float f) {
  union { float f; unsigned u; } v; v.f = f;
  unsigned r = v.u + 0x7fffu + ((v.u >> 16) & 1u);
  return (short)(r >> 16);
}

// ---------------- Projection (+ fused Wo transpose) ----------------
// K is stored PERMUTED: within each 32-row chunk, key row k goes to physical row
// swap23(k) (bits 2<->3). This makes the attn QK^T score layout line up exactly with
// the PV B-operand fragment layout -> no cross-lane exchange needed in attention.
__global__ __launch_bounds__(256) void proj_kernel(
    const float* __restrict__ x, const float* __restrict__ Wq,
    const float* __restrict__ Wk, const float* __restrict__ Wv,
    const float* __restrict__ Wo,
    short* __restrict__ Q, short* __restrict__ K, short* __restrict__ VT,
    short* __restrict__ WoT)
{
  __shared__ float xs[8][128];
  const int tid = threadIdx.x;
  const int row0 = blockIdx.x * 8;
  {
    const float4* src = (const float4*)(x + (size_t)row0 * 128);
    float4* dst = (float4*)xs;
    dst[tid] = src[tid];
  }
  if (blockIdx.x < 256)
    WoT[blockIdx.x * 256 + tid] = f2bf(Wo[tid * 256 + blockIdx.x]);
  __syncthreads();
  const int c = tid;
  float qa[8], ka[8], va[8];
#pragma unroll
  for (int r = 0; r < 8; ++r) { qa[r] = 0.f; ka[r] = 0.f; va[r] = 0.f; }
  for (int d4 = 0; d4 < 16; ++d4) {
    float wq[4], wk[4], wv[4];
#pragma unroll
    for (int j = 0; j < 4; ++j) {
      const int d = d4 * 4 + j;
      wq[j] = Wq[d * 256 + c];
      wk[j] = Wk[d * 256 + c];
      wv[j] = Wv[d * 256 + c];
    }
#pragma unroll
    for (int r = 0; r < 8; ++r) {
      const float4 xt = *(const float4*)&xs[r][d4 * 4];
      const float4 xp = *(const float4*)&xs[r][64 + d4 * 4];
      qa[r] += xp.x * wq[0] + xp.y * wq[1] + xp.z * wq[2] + xp.w * wq[3];
      ka[r] += xp.x * wk[0] + xp.y * wk[1] + xp.z * wk[2] + xp.w * wk[3];
      va[r] += xt.x * wv[0] + xt.y * wv[1] + xt.z * wv[2] + xt.w * wv[3];
    }
  }
  const int b = row0 >> 12;
  const int t0 = row0 & 4095;
  const int h = c >> 5, d = c & 31;
  const int bh = b * NHD + h;
#pragma unroll
  for (int r = 0; r < 8; ++r) {
    const int row = t0 + r;
    Q[(bh * SEQ + row) * HDIM + d] = f2bf(qa[r] * QSCALE);
    // swap bits 2,3 of the within-chunk index
    const int prow = (row & ~31) | (row & 19) | ((row & 4) << 1) | ((row & 8) >> 1);
    K[(bh * SEQ + prow) * HDIM + d] = f2bf(ka[r]);
  }
  bf16x8 vv;
#pragma unroll
  for (int r = 0; r < 8; ++r) vv[r] = f2bf(va[r]);
  *(bf16x8*)&VT[(size_t)(bh * HDIM + d) * SEQ + t0] = vv;
}

// ---- scores -> exp2 -> packed bf16 P fragments; NO cross-lane ops.
// With K pre-permuted, S reg r (half hi) is the score of key kb + koff where
// koff = (r&3) + 4*((r>>2)&1) + 16*((r>>3)&1) + 8*hi, and cvt_pk of consecutive
// S regs lands exactly in PV B-fragment word order (pairs 0..3 -> mfma0 w0..3,
// pairs 4..7 -> mfma1 w0..3).
template <bool MASKED>
__device__ __forceinline__ void score_to_p(const f32x16& S, int hi, int l31,
                                           float& lsum, bf16x8& p0v, bf16x8& p1v)
{
  union { unsigned u[4]; bf16x8 v; } p0, p1;
#pragma unroll
  for (int i = 0; i < 8; ++i) {
    const int r0 = 2 * i;
    float e0, e1;
    if (MASKED) {
      const int koff = (r0 & 3) + (((r0 >> 2) & 1) << 2) + (((r0 >> 3) & 1) << 4) + (hi << 3);
      e0 = (koff     <= l31) ? __builtin_amdgcn_exp2f(S[r0])     : 0.f;
      e1 = (koff + 1 <= l31) ? __builtin_amdgcn_exp2f(S[r0 + 1]) : 0.f;
    } else {
      e0 = __builtin_amdgcn_exp2f(S[r0]);
      e1 = __builtin_amdgcn_exp2f(S[r0 + 1]);
    }
    lsum += e0 + e1;
    unsigned wd;
    asm("v_cvt_pk_bf16_f32 %0, %1, %2" : "=v"(wd) : "v"(e0), "v"(e1));
    if (i < 4) p0.u[i] = wd; else p1.u[i - 4] = wd;
  }
  p0v = p0.v; p1v = p1.v;
}

// ---------------- Causal attention: paired tiles + prefetch + split-K x4 ----------------
// 1024 blocks = 16 bh x 64 pairs (A=p, B=127-p): every block exactly 129 chunk-visits.
// Both tiles share each chunk's K/V loads; next chunk prefetched into registers.
// Fixed-max (m=0) softmax -> split-K partials (acc,lsum) merge by addition via LDS.
__global__ __launch_bounds__(256, 4) void attn_kernel(
    const short* __restrict__ Q, const short* __restrict__ K,
    const short* __restrict__ VT, short* __restrict__ O)
{
  __shared__ float MG[8][17][64];

  const int flat = blockIdx.x;
  const int bh = (flat & 7) + (((flat >> 3) & 1) << 3);   // XCD x serves bh {x, x+8}
  const int p = flat >> 4;                                 // pair 0..63
  const int tA = p, tB = 127 - p;
  const int q0A = tA << 5, q0B = tB << 5;
  const int ncA = tA + 1, ncB = tB + 1;

  const int w = threadIdx.x >> 6;
  const int lane = threadIdx.x & 63;
  const int l31 = lane & 31;
  const int hi = lane >> 5;

  const short* Kb  = K  + (size_t)bh * SEQ * HDIM;
  const short* VTb = VT + (size_t)bh * HDIM * SEQ;

  const short* qrowA = &Q[((size_t)bh * SEQ + q0A + l31) * HDIM + hi * 8];
  const bf16x8 qfA0 = *(const bf16x8*)qrowA;
  const bf16x8 qfA1 = *(const bf16x8*)(qrowA + 16);
  const short* qrowB = &Q[((size_t)bh * SEQ + q0B + l31) * HDIM + hi * 8];
  const bf16x8 qfB0 = *(const bf16x8*)qrowB;
  const bf16x8 qfB1 = *(const bf16x8*)(qrowB + 16);

  const f32x16 z16 = {0.f,0.f,0.f,0.f,0.f,0.f,0.f,0.f,0.f,0.f,0.f,0.f,0.f,0.f,0.f,0.f};
  f32x16 accA = z16, accB = z16;
  float lsumA = 0.f, lsumB = 0.f;

  int c = w;
  bf16x8 kf0, kf1, vf0, vf1;
  {
    const int kb = c << 5;
    const short* krow = &Kb[(size_t)(kb + l31) * HDIM + hi * 8];
    kf0 = *(const bf16x8*)krow;
    kf1 = *(const bf16x8*)(krow + 16);
    const short* vrow = &VTb[(size_t)l31 * SEQ + kb + hi * 8];
    vf0 = *(const bf16x8*)vrow;
    vf1 = *(const bf16x8*)(vrow + 16);
  }

  // ---- phase 1: both tiles (c < ncA); B is never masked here ----
  for (; c < ncA; c += 4) {
    const int kb = c << 5;
    const int cn = c + 4;
    bf16x8 kn0, kn1, vn0, vn1;
    if (cn < ncB) {
      const int kbn = cn << 5;
      const short* krow = &Kb[(size_t)(kbn + l31) * HDIM + hi * 8];
      kn0 = *(const bf16x8*)krow;
      kn1 = *(const bf16x8*)(krow + 16);
      const short* vrow = &VTb[(size_t)l31 * SEQ + kbn + hi * 8];
      vn0 = *(const bf16x8*)vrow;
      vn1 = *(const bf16x8*)(vrow + 16);
    }
    {
      f32x16 S = __builtin_amdgcn_mfma_f32_32x32x16_bf16(kf0, qfB0, z16, 0, 0, 0);
      S = __builtin_amdgcn_mfma_f32_32x32x16_bf16(kf1, qfB1, S, 0, 0, 0);
      bf16x8 p0v, p1v;
      score_to_p<false>(S, hi, l31, lsumB, p0v, p1v);
      accB = __builtin_amdgcn_mfma_f32_32x32x16_bf16(vf0, p0v, accB, 0, 0, 0);
      accB = __builtin_amdgcn_mfma_f32_32x32x16_bf16(vf1, p1v, accB, 0, 0, 0);
    }
    {
      f32x16 S = __builtin_amdgcn_mfma_f32_32x32x16_bf16(kf0, qfA0, z16, 0, 0, 0);
      S = __builtin_amdgcn_mfma_f32_32x32x16_bf16(kf1, qfA1, S, 0, 0, 0);
      bf16x8 p0v, p1v;
      if (kb == q0A) score_to_p<true >(S, hi, l31, lsumA, p0v, p1v);
      else           score_to_p<false>(S, hi, l31, lsumA, p0v, p1v);
      accA = __builtin_amdgcn_mfma_f32_32x32x16_bf16(vf0, p0v, accA, 0, 0, 0);
      accA = __builtin_amdgcn_mfma_f32_32x32x16_bf16(vf1, p1v, accA, 0, 0, 0);
    }
    kf0 = kn0; kf1 = kn1; vf0 = vn0; vf1 = vn1;
  }

  // ---- phase 2: tile B only ----
  for (; c < ncB; c += 4) {
    const int kb = c << 5;
    const int cn = c + 4;
    bf16x8 kn0, kn1, vn0, vn1;
    if (cn < ncB) {
      const int kbn = cn << 5;
      const short* krow = &Kb[(size_t)(kbn + l31) * HDIM + hi * 8];
      kn0 = *(const bf16x8*)krow;
      kn1 = *(const bf16x8*)(krow + 16);
      const short* vrow = &VTb[(size_t)l31 * SEQ + kbn + hi * 8];
      vn0 = *(const bf16x8*)vrow;
      vn1 = *(const bf16x8*)(vrow + 16);
    }
    f32x16 S = __builtin_amdgcn_mfma_f32_32x32x16_bf16(kf0, qfB0, z16, 0, 0, 0);
    S = __builtin_amdgcn_mfma_f32_32x32x16_bf16(kf1, qfB1, S, 0, 0, 0);
    bf16x8 p0v, p1v;
    if (kb == q0B) score_to_p<true >(S, hi, l31, lsumB, p0v, p1v);
    else           score_to_p<false>(S, hi, l31, lsumB, p0v, p1v);
    accB = __builtin_amdgcn_mfma_f32_32x32x16_bf16(vf0, p0v, accB, 0, 0, 0);
    accB = __builtin_amdgcn_mfma_f32_32x32x16_bf16(vf1, p1v, accB, 0, 0, 0);
    kf0 = kn0; kf1 = kn1; vf0 = vn0; vf1 = vn1;
  }

  // ---- split-K merge: publish (acc, lsum) per tile; waves 0/1 reduce + store ----
#pragma unroll
  for (int i = 0; i < 16; ++i) MG[w][i][lane] = accA[i];
  MG[w][16][lane] = lsumA;
#pragma unroll
  for (int i = 0; i < 16; ++i) MG[4 + w][i][lane] = accB[i];
  MG[4 + w][16][lane] = lsumB;
  __syncthreads();
  if (w < 2) {
    const int base = w << 2;
    const int q0 = w ? q0B : q0A;
    float fa[16];
#pragma unroll
    for (int i = 0; i < 16; ++i) fa[i] = 0.f;
    float fl = 0.f;
#pragma unroll
    for (int w2 = 0; w2 < 4; ++w2) {
#pragma unroll
      for (int i = 0; i < 16; ++i) fa[i] += MG[base + w2][i][lane];
      fl += MG[base + w2][16][lane] + MG[base + w2][16][lane ^ 32];
    }
    const float inv = 1.f / fl;
    const size_t obase = ((size_t)bh * SEQ + q0 + l31) * HDIM;
#pragma unroll
    for (int rg = 0; rg < 4; ++rg) {
      const int d0 = (rg << 3) + (hi << 2);
      short4 st;
      st.x = f2bf(fa[rg * 4 + 0] * inv);
      st.y = f2bf(fa[rg * 4 + 1] * inv);
      st.z = f2bf(fa[rg * 4 + 2] * inv);
      st.w = f2bf(fa[rg * 4 + 3] * inv);
      *(short4*)&O[obase + d0] = st;
    }
  }
}

// ---------------- out = O_cat @ Wo : 8192 x 256 x 256 ----------------
// grid (128,8): 1024 blocks x 4 waves = 4096 waves (4/SIMD). Wave = 16 rows x 32 cols,
// next-ks A/B register prefetch.
__global__ __launch_bounds__(256) void ogemm_kernel(
    const short* __restrict__ O, const short* __restrict__ WoT, float* __restrict__ out)
{
  const int w = threadIdx.x >> 6;
  const int lane = threadIdx.x & 63;
  const int l15 = lane & 15, g = lane >> 4;
  const int m0 = blockIdx.x * 64 + w * 16;
  const int n0 = blockIdx.y * 32;
  const int b = m0 >> 12;
  const int t = (m0 & 4095) + l15;

  const short* Ab = &O[(((size_t)b * NHD) * SEQ + t) * HDIM + g * 8];
  const short* B0 = &WoT[(n0 + l15) * 256 + g * 8];
  const short* B1 = &WoT[(n0 + 16 + l15) * 256 + g * 8];

  f32x4 acc0 = {0.f, 0.f, 0.f, 0.f}, acc1 = {0.f, 0.f, 0.f, 0.f};
  bf16x8 af = *(const bf16x8*)Ab;
  bf16x8 b0 = *(const bf16x8*)B0;
  bf16x8 b1 = *(const bf16x8*)B1;
#pragma unroll
  for (int ks = 0; ks < 8; ++ks) {
    bf16x8 an, bn0, bn1;
    if (ks < 7) {
      an  = *(const bf16x8*)(Ab + (size_t)(ks + 1) * SEQ * HDIM);
      bn0 = *(const bf16x8*)(B0 + (ks + 1) * 32);
      bn1 = *(const bf16x8*)(B1 + (ks + 1) * 32);
    }
    acc0 = __builtin_amdgcn_mfma_f32_16x16x32_bf16(af, b0, acc0, 0, 0, 0);
    acc1 = __builtin_amdgcn_mfma_f32_16x16x32_bf16(af, b1, acc1, 0, 0, 0);
    af = an; b0 = bn0; b1 = bn1;
  }
#pragma unroll
  for (int r = 0; r < 4; ++r) {
    const size_t ro = (size_t)(m0 + (g << 2) + r) * 256 + n0 + l15;
    out[ro] = acc0[r];
    out[ro + 16] = acc1[r];
  }
}

extern "C" void kernel_launch(void* const* d_in, const int* in_sizes, int n_in,
                              void* d_out, int out_size, void* d_ws, size_t ws_size,
                              hipStream_t stream)
{
  const float* x  = (const float*)d_in[0];
  const float* Wq = (const float*)d_in[1];
  const float* Wk = (const float*)d_in[2];
  const float* Wv = (const float*)d_in[3];
  const float* Wo = (const float*)d_in[4];
  float* out = (float*)d_out;

  short* Q   = (short*)d_ws;
  short* K   = Q + 2097152;            // chunk-permuted (bits 2<->3 of row%32)
  short* VT  = K + 2097152;            // (B,H,D,T)
  short* O   = VT + 2097152;           // (B,H,T,D)
  short* WoT = O + 2097152;

  proj_kernel<<<dim3(1024), dim3(256), 0, stream>>>(x, Wq, Wk, Wv, Wo, Q, K, VT, WoT);
  attn_kernel<<<dim3(1024), dim3(256), 0, stream>>>(Q, K, VT, O);
  ogemm_kernel<<<dim3(128, 8), dim3(256), 0, stream>>>(O, WoT, out);
}